// Round 1
// 253.327 us; speedup vs baseline: 1.3662x; 1.3662x over previous
//
#include <hip/hip_runtime.h>
#include <math.h>

// ---- problem constants ----
#define N_SAMP 441000
#define BATCH  16
#define N_OCT  55125           // octs (8-sample groups) per row
#define OPAD   55296           // padded octs: 216 chunks * 256
#define NMG    13824           // OPAD/4 macro-groups (4 octs each)
#define MGF    576             // floats per macro-group: 9 planes * 64 (16b*4slot)
#define MGB    2304            // bytes per macro-group
#define NWAVE  54              // 216 chunks / 4 per wave

#define A_AT  0.9977349953069123f
#define A_REL 0.9997732683378945f
#define OMA_AT  (1.0f - A_AT)
#define OMA_REL (1.0f - A_REL)

typedef float vf4 __attribute__((ext_vector_type(4)));

static __device__ __forceinline__ float rect_db_f(float xv) {
    return 6.020599913279624f * log2f(fabsf(xv) + 1e-8f);
}
static __device__ __forceinline__ float step_v(float s, float v) {
    return fmaxf(fmaf(A_AT, s, OMA_AT * v), fmaf(A_REL, s, OMA_REL * v));
}
static __device__ __forceinline__ float max3f(float a, float b, float c) {
    float d;
    asm("v_max3_f32 %0, %1, %2, %3" : "=v"(d) : "v"(a), "v"(b), "v"(c));
    return d;
}
static __device__ __forceinline__ float gain_mul(float s, float th, float dp) {
    float ddn = s - th;
    float gdn = 0.0f;
    if (ddn > -0.1f) {
        float dm = ddn - 0.1f;
        gdn = -0.4925037481259370f * (ddn + 0.1f + sqrtf(fmaf(dm, dm, 1e-4f)));
    }
    float dup = th - s;
    float gup = 0.0f;
    if (dup > -0.1f) {
        float um = dup - 0.1f;
        gup = 0.45f * (dup + 0.1f + sqrtf(fmaf(um, um, 1e-4f)));
    }
    gup = fminf(gup, 36.0f);
    return exp2f((gdn + gup) * dp * 0.1660964047443681f);
}

// ---- Pass 0: 9 composite coefficients per 8-sample oct (max-plus DP) ----
// K layout: [mg][plane 0..8][b*4 + slot]  (mg = group of 4 octs)
__global__ __launch_bounds__(256) void coef8_kernel(const float* __restrict__ x,
                                                    float* __restrict__ K) {
    int l = blockIdx.x * 256 + threadIdx.x;
    int slot = l & 3, b = (l >> 2) & 15, mg = l >> 6;
    int o = mg * 4 + slot;
    if (o >= N_OCT) return;
    const float4* xp = (const float4*)(x + (size_t)b * N_SAMP + (size_t)o * 8);
    float4 xa = xp[0], xb = xp[1];
    float vv[8];
    vv[0] = rect_db_f(xa.x); vv[1] = rect_db_f(xa.y);
    vv[2] = rect_db_f(xa.z); vv[3] = rect_db_f(xa.w);
    vv[4] = rect_db_f(xb.x); vv[5] = rect_db_f(xb.y);
    vv[6] = rect_db_f(xb.z); vv[7] = rect_db_f(xb.w);
    float c[9];
    c[0] = OMA_REL * vv[0];
    c[1] = OMA_AT * vv[0];
    #pragma unroll
    for (int j = 1; j < 8; ++j) {
        float p = OMA_AT * vv[j], q = OMA_REL * vv[j];
        c[j + 1] = fmaf(A_AT, c[j], p);
        #pragma unroll
        for (int m = j; m >= 1; --m)
            c[m] = fmaxf(fmaf(A_AT, c[m - 1], p), fmaf(A_REL, c[m], q));
        c[0] = fmaf(A_REL, c[0], q);
    }
    float* kp = K + (size_t)mg * MGF + (b * 4 + slot);
    #pragma unroll
    for (int pl = 0; pl < 9; ++pl) kp[pl * 64] = c[pl];
}

// ---- Pass 1: serial scan, 8-sample jumps, 4-deep rotating register buffers,
//      volatile-asm loads + hand-counted vmcnt (compiler cannot collapse) ----
__global__ __launch_bounds__(64, 1) void scan8_kernel(const float* __restrict__ Kf,
                                                      const float* __restrict__ x,
                                                      float* __restrict__ lvl) {
    int wb = blockIdx.x;
    // m204 bijective XCD-chunked swizzle (54 = 8*6 + 6): consecutive chunks share L2
    int xcd = wb & 7, jj = wb >> 3;
    int w = (xcd < 6 ? xcd * 7 : 42 + (xcd - 6) * 6) + jj;
    const int lane = threadIdx.x;
    const int grp = lane >> 4, b = lane & 15;
    const int k = 4 * w + grp;               // chunk id 0..215 (256 octs each)

    constexpr double dAT = 0.9977349953069123, dRL = 0.9997732683378945;
    constexpr double dAT2 = dAT * dAT, dAT4 = dAT2 * dAT2;
    constexpr double dRL2 = dRL * dRL, dRL4 = dRL2 * dRL2;
    const float S0 = (float)(dRL4 * dRL4);
    const float S1 = (float)(dAT * dRL4 * dRL2 * dRL);
    const float S2 = (float)(dAT2 * dRL4 * dRL2);
    const float S3 = (float)(dAT2 * dAT * dRL4 * dRL);
    const float S4 = (float)(dAT4 * dRL4);
    const float S5 = (float)(dAT4 * dAT * dRL2 * dRL);
    const float S6 = (float)(dAT4 * dAT2 * dRL2);
    const float S7 = (float)(dAT4 * dAT2 * dAT * dRL);
    const float S8 = (float)(dAT4 * dAT4);

    vf4 R0[9], R1[9], R2[9], R3[9];
    vf4 lv;
    float s;
    unsigned voff;
    float* lq;
    float* dq = lvl + (size_t)16 * OPAD + lane * 4;   // dump slots (values unused)

#define LDB(R) do {                                                                              \
    asm volatile("global_load_dwordx4 %0, %1, %2 offset:0"    : "=v"(R[0]) : "v"(voff), "s"(Kf)); \
    asm volatile("global_load_dwordx4 %0, %1, %2 offset:256"  : "=v"(R[1]) : "v"(voff), "s"(Kf)); \
    asm volatile("global_load_dwordx4 %0, %1, %2 offset:512"  : "=v"(R[2]) : "v"(voff), "s"(Kf)); \
    asm volatile("global_load_dwordx4 %0, %1, %2 offset:768"  : "=v"(R[3]) : "v"(voff), "s"(Kf)); \
    asm volatile("global_load_dwordx4 %0, %1, %2 offset:1024" : "=v"(R[4]) : "v"(voff), "s"(Kf)); \
    asm volatile("global_load_dwordx4 %0, %1, %2 offset:1280" : "=v"(R[5]) : "v"(voff), "s"(Kf)); \
    asm volatile("global_load_dwordx4 %0, %1, %2 offset:1536" : "=v"(R[6]) : "v"(voff), "s"(Kf)); \
    asm volatile("global_load_dwordx4 %0, %1, %2 offset:1792" : "=v"(R[7]) : "v"(voff), "s"(Kf)); \
    asm volatile("global_load_dwordx4 %0, %1, %2 offset:2048" : "=v"(R[8]) : "v"(voff), "s"(Kf)); \
    voff += MGB;                                                                                  \
} while (0)

// steady state: 3 younger buffers * 9 loads = 27 outstanding allowed; in-order
// vmcnt decrement => target buffer's 9 loads are guaranteed complete. Stores
// interleaved in emit phases only make this an over-wait (still correct).
#define WAITP() do {                                       \
    asm volatile("s_waitcnt vmcnt(27)" ::: "memory");      \
    __builtin_amdgcn_sched_barrier(0);                     \
} while (0)

#define CMP(R) do {                                        \
    _Pragma("unroll")                                      \
    for (int _e = 0; _e < 4; ++_e) {                       \
        float c0 = fmaf(S0, s, R[0][_e]);                  \
        float c1 = fmaf(S1, s, R[1][_e]);                  \
        float c2 = fmaf(S2, s, R[2][_e]);                  \
        float c3 = fmaf(S3, s, R[3][_e]);                  \
        float c4 = fmaf(S4, s, R[4][_e]);                  \
        float c5 = fmaf(S5, s, R[5][_e]);                  \
        float c6 = fmaf(S6, s, R[6][_e]);                  \
        float c7 = fmaf(S7, s, R[7][_e]);                  \
        float c8 = fmaf(S8, s, R[8][_e]);                  \
        s = max3f(max3f(c0, c1, c2), max3f(c3, c4, c5), max3f(c6, c7, c8)); \
        lv[_e] = s;                                        \
    }                                                      \
} while (0)

#define PH_W(R) do { WAITP(); CMP(R); LDB(R); } while (0)
#define PH_E(R) do { WAITP(); CMP(R);                      \
    lq[0] = lv[0]; lq[16] = lv[1]; lq[32] = lv[2]; lq[48] = lv[3]; lq += 64; \
    LDB(R); } while (0)
#define PH_D(R) do { WAITP(); CMP(R); {                    \
    float* _sp = ((unsigned)(sb - kw) < 64u) ? lq : dq;    \
    _sp[0] = lv[0]; _sp[16] = lv[1]; _sp[32] = lv[2]; _sp[48] = lv[3]; }   \
    lq += 64; ++sb; LDB(R); } while (0)

    if (w >= 4) {
        // full warmup: 4096 octs = 1024 macro-groups before the chunk
        const int g0 = (k - 16) * 64;                 // start macro-group
        s = rect_db_f(x[(size_t)b * N_SAMP + (size_t)g0 * 32]);
        asm volatile("" :: "v"(s));                   // pin init load before asm region
        voff = (unsigned)g0 * MGB + (unsigned)b * 16u;
        LDB(R0); LDB(R1); LDB(R2); LDB(R3);
        #pragma clang loop unroll(disable)
        for (int it = 0; it < 256; ++it) { PH_W(R0); PH_W(R1); PH_W(R2); PH_W(R3); }
        lq = lvl + (size_t)k * 256 * 16 + b;          // transposed [oct][b]
        #pragma clang loop unroll(disable)
        for (int it = 0; it < 16; ++it) { PH_E(R0); PH_E(R1); PH_E(R2); PH_E(R3); }
    } else {
        // chunks 0..15 start at sample 0 (exact history, no truncation)
        const int nit = (4 * w + 4) * 16;             // iterations of 4 phases
        s = rect_db_f(x[(size_t)b * N_SAMP]);
        asm volatile("" :: "v"(s));
        voff = (unsigned)b * 16u;
        int sb = 0;
        const unsigned kw = (unsigned)(k << 6);       // emit window [k*64, k*64+64)
        lq = lvl + b;
        LDB(R0); LDB(R1); LDB(R2); LDB(R3);
        #pragma clang loop unroll(disable)
        for (int it = 0; it < nit; ++it) { PH_D(R0); PH_D(R1); PH_D(R2); PH_D(R3); }
    }
    asm volatile("s_waitcnt vmcnt(0)" ::: "memory");

#undef LDB
#undef WAITP
#undef CMP
#undef PH_W
#undef PH_E
#undef PH_D
}

// ---- Pass 2: intra-oct reconstruction + gain + output (parallel) ----
__global__ __launch_bounds__(256) void out8_kernel(const float* __restrict__ x,
                                                   const float* __restrict__ lvl,
                                                   const float* __restrict__ thr,
                                                   const float* __restrict__ dep,
                                                   float* __restrict__ out) {
    int o = blockIdx.x * 256 + threadIdx.x;
    int b = blockIdx.y;
    if (o >= N_OCT) return;
    const float4* xp = (const float4*)(x + (size_t)b * N_SAMP + (size_t)o * 8);
    float4 xa = xp[0], xb = xp[1];
    float v0 = rect_db_f(xa.x), v1 = rect_db_f(xa.y);
    float v2 = rect_db_f(xa.z), v3 = rect_db_f(xa.w);
    float v4 = rect_db_f(xb.x), v5 = rect_db_f(xb.y);
    float v6 = rect_db_f(xb.z), v7 = rect_db_f(xb.w);
    float s = (o == 0) ? v0 : lvl[(size_t)(o - 1) * 16 + b];
    float l0 = step_v(s, v0);
    float l1 = step_v(l0, v1);
    float l2 = step_v(l1, v2);
    float l3 = step_v(l2, v3);
    float l4 = step_v(l3, v4);
    float l5 = step_v(l4, v5);
    float l6 = step_v(l5, v6);
    float l7 = step_v(l6, v7);
    float th = fmaf(thr[b], 40.0f, -40.0f);
    float dp = dep[b];
    float4 oa, ob;
    oa.x = xa.x * gain_mul(l0, th, dp);
    oa.y = xa.y * gain_mul(l1, th, dp);
    oa.z = xa.z * gain_mul(l2, th, dp);
    oa.w = xa.w * gain_mul(l3, th, dp);
    ob.x = xb.x * gain_mul(l4, th, dp);
    ob.y = xb.y * gain_mul(l5, th, dp);
    ob.z = xb.z * gain_mul(l6, th, dp);
    ob.w = xb.w * gain_mul(l7, th, dp);
    float4* op = (float4*)(out + (size_t)b * N_SAMP + (size_t)o * 8);
    op[0] = oa;
    op[1] = ob;
}

// ---- Fallback (tiny ws): slow but correct fused scan ----
__global__ __launch_bounds__(64) void scan_fused(const float* __restrict__ x,
                                                 const float* __restrict__ thr,
                                                 const float* __restrict__ dep,
                                                 float* __restrict__ out) {
    int t = blockIdx.x * 64 + threadIdx.x;
    const int NCH = 54, CH = 8192, WM = 32768;
    if (t >= BATCH * NCH) return;
    int b = t / NCH, k = t - b * NCH;
    int start = k * CH, end = min(start + CH, N_SAMP), w0 = max(start - WM, 0);
    const float* xr = x + (size_t)b * N_SAMP;
    float th = fmaf(thr[b], 40.0f, -40.0f);
    float dp = dep[b];
    float s = rect_db_f(xr[w0]);
    for (int j = w0; j < start; ++j) s = step_v(s, rect_db_f(xr[j]));
    float* orow = out + (size_t)b * N_SAMP;
    for (int j = start; j < end; ++j) {
        float xv = xr[j];
        s = step_v(s, rect_db_f(xv));
        orow[j] = xv * gain_mul(s, th, dp);
    }
}

extern "C" void kernel_launch(void* const* d_in, const int* in_sizes, int n_in,
                              void* d_out, int out_size, void* d_ws, size_t ws_size,
                              hipStream_t stream) {
    const float* x   = (const float*)d_in[0];
    const float* thr = (const float*)d_in[1];
    const float* dep = (const float*)d_in[2];
    float* out = (float*)d_out;

    const size_t k_bytes   = (size_t)NMG * MGF * sizeof(float);            // 31.85 MB
    const size_t lvl_bytes = ((size_t)16 * OPAD + 512) * sizeof(float);    // 3.54 MB + dump

    if (ws_size >= k_bytes + lvl_bytes) {
        float* K   = (float*)d_ws;
        float* lvl = (float*)((char*)d_ws + k_bytes);
        coef8_kernel<<<(NMG * 64) / 256, 256, 0, stream>>>(x, K);
        scan8_kernel<<<NWAVE, 64, 0, stream>>>(K, x, lvl);
        dim3 gpar((N_OCT + 255) / 256, BATCH);
        out8_kernel<<<gpar, 256, 0, stream>>>(x, lvl, thr, dep, out);
    } else {
        scan_fused<<<(BATCH * 54 + 63) / 64, 64, 0, stream>>>(x, thr, dep, out);
    }
}